// Round 1
// baseline (224.641 us; speedup 1.0000x reference)
//
#include <hip/hip_runtime.h>
#include <hip/hip_bf16.h>
#include <stdint.h>

typedef unsigned short u16;
typedef __attribute__((ext_vector_type(8))) __bf16 bf16x8;
typedef __attribute__((ext_vector_type(8))) unsigned short us8;
typedef __attribute__((ext_vector_type(4))) unsigned short us4;
typedef __attribute__((ext_vector_type(4))) float f32x4;

__device__ inline u16 f2bf(float f) {
  union { float f; unsigned int u; } x; x.f = f;
  unsigned int u = x.u;
  u += 0x7fffu + ((u >> 16) & 1u);
  return (u16)(u >> 16);
}
__device__ inline float bf2f(u16 u) {
  union { unsigned int u; float f; } x; x.u = ((unsigned int)u) << 16;
  return x.f;
}
__device__ inline __bf16 bfbits(u16 u) {
  union { u16 s; __bf16 b; } x; x.s = u; return x.b;
}

// ---------------------------------------------------------------- conversions
__global__ __launch_bounds__(256) void f32_to_bf16_vec(
    const float* __restrict__ in, u16* __restrict__ out) {
  int i = blockIdx.x * 256 + threadIdx.x;
  const float4 v = ((const float4*)in)[i];
  us4 o;
  o[0] = f2bf(v.x); o[1] = f2bf(v.y); o[2] = f2bf(v.z); o[3] = f2bf(v.w);
  ((us4*)out)[i] = o;
}

// in [R][C] fp32 -> outT [C][R] bf16
__global__ void transpose_bf16(const float* __restrict__ in,
                               u16* __restrict__ outT, int R, int C) {
  __shared__ float tile[32][33];
  int c0 = blockIdx.x * 32, r0 = blockIdx.y * 32;
  int x = threadIdx.x, y = threadIdx.y; // block (32,8)
  for (int j = 0; j < 32; j += 8)
    tile[y + j][x] = in[(size_t)(r0 + y + j) * C + c0 + x];
  __syncthreads();
  for (int j = 0; j < 32; j += 8)
    outT[(size_t)(c0 + y + j) * R + r0 + x] = f2bf(tile[x][y + j]);
}

// ---------------------------------------------------------------- GEMM
// C[M][N] = A[M][K] @ Bt[N][K]^T + bias[N]; A,Bt bf16; OB=1 -> bf16 out else f32
// block 256 (4 waves as 2x2), tile 128x128, BK=32.
#define LDST 40  // LDS row stride in halves: 80B = 16B-aligned, banks spread
template <int OB>
__global__ __launch_bounds__(256) void gemm_bt(
    const u16* __restrict__ A, const u16* __restrict__ Bt,
    const float* __restrict__ bias, void* __restrict__ Cout,
    int M, int N, int K) {
  __shared__ __align__(16) u16 As[128 * LDST];
  __shared__ __align__(16) u16 Bs[128 * LDST];
  int tid = threadIdx.x;
  int wave = tid >> 6, lane = tid & 63, quad = lane >> 4, l16 = lane & 15;
  int wm = (wave >> 1) * 64, wn = (wave & 1) * 64;
  int m0 = blockIdx.y * 128, n0 = blockIdx.x * 128;
  f32x4 acc[4][4];
  for (int i = 0; i < 4; ++i)
    for (int j = 0; j < 4; ++j) acc[i][j] = (f32x4){0.f, 0.f, 0.f, 0.f};

  int sr = tid >> 1;         // 0..127
  int sc = (tid & 1) * 16;   // 0 / 16

  for (int kk = 0; kk < K; kk += 32) {
    us8 a0 = *(const us8*)(A + (size_t)(m0 + sr) * K + kk + sc);
    us8 a1 = *(const us8*)(A + (size_t)(m0 + sr) * K + kk + sc + 8);
    us8 b0 = *(const us8*)(Bt + (size_t)(n0 + sr) * K + kk + sc);
    us8 b1 = *(const us8*)(Bt + (size_t)(n0 + sr) * K + kk + sc + 8);
    __syncthreads();
    *(us8*)(As + sr * LDST + sc) = a0;
    *(us8*)(As + sr * LDST + sc + 8) = a1;
    *(us8*)(Bs + sr * LDST + sc) = b0;
    *(us8*)(Bs + sr * LDST + sc + 8) = b1;
    __syncthreads();
    bf16x8 af[4], bfr[4];
    for (int i = 0; i < 4; ++i)
      af[i] = *(const bf16x8*)(As + (wm + i * 16 + l16) * LDST + quad * 8);
    for (int i = 0; i < 4; ++i)
      bfr[i] = *(const bf16x8*)(Bs + (wn + i * 16 + l16) * LDST + quad * 8);
    for (int mi = 0; mi < 4; ++mi)
      for (int ni = 0; ni < 4; ++ni)
        acc[mi][ni] = __builtin_amdgcn_mfma_f32_16x16x32_bf16(
            af[mi], bfr[ni], acc[mi][ni], 0, 0, 0);
  }
  for (int ni = 0; ni < 4; ++ni) {
    int col = n0 + wn + ni * 16 + l16;
    float bv = bias[col];
    for (int mi = 0; mi < 4; ++mi) {
      int row = m0 + wm + mi * 16 + quad * 4;
      for (int r = 0; r < 4; ++r) {
        float v = acc[mi][ni][r] + bv;
        if (OB)
          ((u16*)Cout)[(size_t)(row + r) * N + col] = f2bf(v);
        else
          ((float*)Cout)[(size_t)(row + r) * N + col] = v;
      }
    }
  }
}

// ---------------------------------------------------------------- attention
// qkv [B*S][1536] bf16 (q|k|v each 512 = 8 heads x 64)
// computes aout[b*S+q][h*64+d] bf16, flash-style, S^T formulation.
__global__ __launch_bounds__(256) void attn_kernel(
    const u16* __restrict__ qkv, const int* __restrict__ mask,
    u16* __restrict__ aout) {
  const int S = 2048, TH = 1536, H = 512;
  int b = blockIdx.z, h = blockIdx.y, q0 = blockIdx.x * 64;
  int tid = threadIdx.x;
  int wave = tid >> 6, lane = tid & 63, quad = lane >> 4, l16 = lane & 15;

  __shared__ __align__(16) u16 Kt[32 * 72];   // [key][kdim], stride 72 halves
  __shared__ __align__(16) u16 Vt[64 * 40];   // [dcol][key], stride 40 halves
  __shared__ __align__(16) u16 Pw[4][16 * 40];// per-wave P[qrow][key]
  __shared__ float maskadd[32];

  // Q fragment as MFMA B-operand (B[kdim][qrow]), pre-scaled by 1/8 (exact)
  int qrow = b * S + q0 + wave * 16 + l16;
  bf16x8 qf[2];
  for (int half = 0; half < 2; ++half) {
    const us8 raw =
        *(const us8*)(qkv + (size_t)qrow * TH + h * 64 + half * 32 + quad * 8);
    bf16x8 t;
    for (int j = 0; j < 8; ++j) t[j] = bfbits(f2bf(bf2f(raw[j]) * 0.125f));
    qf[half] = t;
  }

  float m = -1e30f, l = 0.f;
  f32x4 o[4];
  for (int c = 0; c < 4; ++c) o[c] = (f32x4){0.f, 0.f, 0.f, 0.f};

  int kkey = tid >> 3, kc8 = (tid & 7) * 8;   // K staging (coalesced)
  int vkey = tid & 31, vc8 = (tid >> 5) * 8;  // V staging (transpose-friendly)

  for (int kt0 = 0; kt0 < S; kt0 += 32) {
    us8 kvv = *(const us8*)(qkv + (size_t)(b * S + kt0 + kkey) * TH + 512 +
                            h * 64 + kc8);
    us8 vv = *(const us8*)(qkv + (size_t)(b * S + kt0 + vkey) * TH + 1024 +
                           h * 64 + vc8);
    __syncthreads();
    *(us8*)(Kt + kkey * 72 + kc8) = kvv;
    for (int i = 0; i < 8; ++i) Vt[(vc8 + i) * 40 + vkey] = vv[i];
    if (tid < 32)
      maskadd[tid] = (mask[b * S + kt0 + tid] > 0) ? 0.f : -1e30f;
    __syncthreads();

    // S^T tile: rows=keys (C-layout: key = f*16 + quad*4 + r), col=qrow=l16
    float s[8];
    for (int f = 0; f < 2; ++f) {
      bf16x8 k0 = *(const bf16x8*)(Kt + (f * 16 + l16) * 72 + quad * 8);
      bf16x8 k1 = *(const bf16x8*)(Kt + (f * 16 + l16) * 72 + 32 + quad * 8);
      f32x4 sa = (f32x4){0.f, 0.f, 0.f, 0.f};
      sa = __builtin_amdgcn_mfma_f32_16x16x32_bf16(k0, qf[0], sa, 0, 0, 0);
      sa = __builtin_amdgcn_mfma_f32_16x16x32_bf16(k1, qf[1], sa, 0, 0, 0);
      for (int r = 0; r < 4; ++r)
        s[f * 4 + r] = sa[r] + maskadd[f * 16 + quad * 4 + r];
    }
    // online softmax over this 32-key tile (reduction over regs + quads)
    float tmax = s[0];
    for (int i = 1; i < 8; ++i) tmax = fmaxf(tmax, s[i]);
    tmax = fmaxf(tmax, __shfl_xor(tmax, 16));
    tmax = fmaxf(tmax, __shfl_xor(tmax, 32));
    float m_new = fmaxf(m, tmax);
    float alpha = __expf(m - m_new);
    float p[8], tsum = 0.f;
    for (int i = 0; i < 8; ++i) {
      p[i] = __expf(s[i] - m_new);
      tsum += p[i];
    }
    tsum += __shfl_xor(tsum, 16);
    tsum += __shfl_xor(tsum, 32);
    l = l * alpha + tsum;
    m = m_new;
    for (int c = 0; c < 4; ++c)
      for (int r = 0; r < 4; ++r) o[c][r] *= alpha;

    // P (row=qrow, col=key) to wave-private LDS, read back as B-operand
    u16* pw = &Pw[wave][0];
    for (int f = 0; f < 2; ++f)
      for (int r = 0; r < 4; ++r)
        pw[l16 * 40 + f * 16 + quad * 4 + r] = f2bf(p[f * 4 + r]);
    bf16x8 pf = *(const bf16x8*)(pw + l16 * 40 + quad * 8);
    // O^T += V^T * P^T  (A = V^T fragment, contiguous from Vt)
    for (int c = 0; c < 4; ++c) {
      bf16x8 vf = *(const bf16x8*)(Vt + (c * 16 + l16) * 40 + quad * 8);
      o[c] = __builtin_amdgcn_mfma_f32_16x16x32_bf16(vf, pf, o[c], 0, 0, 0);
    }
  }
  float inv = 1.f / l;
  for (int c = 0; c < 4; ++c) {
    us4 pk;
    for (int r = 0; r < 4; ++r) pk[r] = f2bf(o[c][r] * inv);
    *(us4*)(aout + (size_t)qrow * H + h * 64 + c * 16 + quad * 4) = pk;
  }
}

// ---------------------------------------------------------------- launch
extern "C" void kernel_launch(void* const* d_in, const int* in_sizes, int n_in,
                              void* d_out, int out_size, void* d_ws,
                              size_t ws_size, hipStream_t stream) {
  const float* x = (const float*)d_in[0];     // [4,2048,512]
  const int* mask = (const int*)d_in[1];      // [4,2048]
  const float* Wc = (const float*)d_in[2];    // [512,1536]
  const float* bc = (const float*)d_in[3];    // [1536]
  const float* Wo = (const float*)d_in[4];    // [512,512]
  const float* bo = (const float*)d_in[5];    // [512]
  float* out = (float*)d_out;                 // [4,2048,512] fp32

  char* ws = (char*)d_ws;
  u16* xbf  = (u16*)(ws);                     //  8 MB: x bf16 [8192][512]
  u16* wct  = (u16*)(ws + 8388608);           //  1.5 MB: Wc^T [1536][512]
  u16* wot  = (u16*)(ws + 9961472);           //  0.5 MB: Wo^T [512][512]
  u16* qkv  = (u16*)(ws + 10485760);          // 24 MB: qkv bf16 [8192][1536]
  u16* aout = (u16*)(ws + 35651584);          //  8 MB: attn out bf16

  f32_to_bf16_vec<<<4096, 256, 0, stream>>>(x, xbf);
  transpose_bf16<<<dim3(48, 16), dim3(32, 8), 0, stream>>>(Wc, wct, 512, 1536);
  transpose_bf16<<<dim3(16, 16), dim3(32, 8), 0, stream>>>(Wo, wot, 512, 512);
  gemm_bt<1><<<dim3(12, 64), 256, 0, stream>>>(xbf, wct, bc, qkv, 8192, 1536, 512);
  attn_kernel<<<dim3(32, 8, 4), 256, 0, stream>>>(qkv, mask, aout);
  gemm_bt<0><<<dim3(4, 64), 256, 0, stream>>>(aout, wot, bo, out, 8192, 512, 512);
}

// Round 2
// 181.302 us; speedup vs baseline: 1.2390x; 1.2390x over previous
//
#include <hip/hip_runtime.h>
#include <hip/hip_bf16.h>
#include <stdint.h>

typedef unsigned short u16;
typedef __attribute__((ext_vector_type(8))) __bf16 bf16x8;
typedef __attribute__((ext_vector_type(8))) unsigned short us8;
typedef __attribute__((ext_vector_type(4))) unsigned short us4;
typedef __attribute__((ext_vector_type(4))) float f32x4;

__device__ inline u16 f2bf(float f) {
  union { float f; unsigned int u; } x; x.f = f;
  unsigned int u = x.u;
  u += 0x7fffu + ((u >> 16) & 1u);
  return (u16)(u >> 16);
}
__device__ inline float bf2f(u16 u) {
  union { unsigned int u; float f; } x; x.u = ((unsigned int)u) << 16;
  return x.f;
}
__device__ inline __bf16 bfbits(u16 u) {
  union { u16 s; __bf16 b; } x; x.s = u; return x.b;
}
__device__ __forceinline__ void gl_lds16(const u16* g, u16* l) {
  __builtin_amdgcn_global_load_lds(
      (const __attribute__((address_space(1))) void*)g,
      (__attribute__((address_space(3))) void*)l, 16, 0, 0);
}

// ---------------------------------------------------------------- conversions
__global__ __launch_bounds__(256) void f32_to_bf16_vec(
    const float* __restrict__ in, u16* __restrict__ out) {
  int i = blockIdx.x * 256 + threadIdx.x;
  const float4 v = ((const float4*)in)[i];
  us4 o;
  o[0] = f2bf(v.x); o[1] = f2bf(v.y); o[2] = f2bf(v.z); o[3] = f2bf(v.w);
  ((us4*)out)[i] = o;
}

// in [R][C] fp32 -> outT [C][R] bf16
__global__ void transpose_bf16(const float* __restrict__ in,
                               u16* __restrict__ outT, int R, int C) {
  __shared__ float tile[32][33];
  int c0 = blockIdx.x * 32, r0 = blockIdx.y * 32;
  int x = threadIdx.x, y = threadIdx.y; // block (32,8)
  for (int j = 0; j < 32; j += 8)
    tile[y + j][x] = in[(size_t)(r0 + y + j) * C + c0 + x];
  __syncthreads();
  for (int j = 0; j < 32; j += 8)
    outT[(size_t)(c0 + y + j) * R + r0 + x] = f2bf(tile[x][y + j]);
}

// ---------------------------------------------------------------- mask compact
// 1 block / batch. idx[b][0..nb) = positions of valid keys; idx[j>=nb]=0; nbv[b]=nb
__global__ __launch_bounds__(256) void compact_mask(
    const int* __restrict__ mask, int* __restrict__ idx, int* __restrict__ nbv) {
  int b = blockIdx.x, tid = threadIdx.x;
  const int* mrow = mask + b * 2048;
  int4 a = ((const int4*)mrow)[tid * 2];
  int4 c = ((const int4*)mrow)[tid * 2 + 1];
  int v[8] = {a.x, a.y, a.z, a.w, c.x, c.y, c.z, c.w};
  int cnt = 0;
  for (int i = 0; i < 8; ++i) cnt += (v[i] > 0);
  __shared__ int ps[256];
  ps[tid] = cnt;
  __syncthreads();
  for (int off = 1; off < 256; off <<= 1) {
    int x = ps[tid];
    int y = (tid >= off) ? ps[tid - off] : 0;
    __syncthreads();
    ps[tid] = x + y;
    __syncthreads();
  }
  int total = ps[255];
  int pos = ps[tid] - cnt;
  int* ip = idx + b * 2048;
  for (int i = 0; i < 8; ++i)
    if (v[i] > 0) ip[pos++] = tid * 8 + i;
  for (int i = 0; i < 8; ++i) {
    int j = tid * 8 + i;
    if (j >= total) ip[j] = 0;
  }
  if (tid == 0) nbv[b] = total;
}

// ---------------------------------------------------------------- V^T build
// VTc[b][h][d][j] = V[b][idx[b][j]][h][d], j over compacted slots (padded->row0)
__global__ __launch_bounds__(256) void build_vt(
    const u16* __restrict__ qkv, const int* __restrict__ idx,
    const int* __restrict__ nbv, u16* __restrict__ VTc) {
  int b = blockIdx.y, j0 = blockIdx.x * 64, tid = threadIdx.x;
  int nb = nbv[b];
  int npad = (nb + 63) & ~63;
  if (j0 >= npad) return;
  __shared__ __align__(16) u16 Vl[64 * 72];
  __shared__ int jidx[64];
  if (tid < 64) jidx[tid] = idx[b * 2048 + j0 + tid];
  __syncthreads();
  for (int h = 0; h < 8; ++h) {
    for (int rep = 0; rep < 2; ++rep) {
      int id = rep * 256 + tid, j = id >> 3, c = id & 7;
      us8 vv = *(const us8*)(qkv + ((size_t)(b * 2048 + jidx[j])) * 1536 +
                             1024 + h * 64 + c * 8);
      *(us8*)(Vl + j * 72 + c * 8) = vv;
    }
    __syncthreads();
    for (int rep = 0; rep < 2; ++rep) {
      int id = rep * 256 + tid, d = id >> 3, c = id & 7;
      us8 o;
      for (int i = 0; i < 8; ++i) o[i] = Vl[(c * 8 + i) * 72 + d];
      *(us8*)(VTc + ((size_t)(b * 8 + h) * 64 + d) * 2048 + j0 + c * 8) = o;
    }
    __syncthreads();
  }
}

// ---------------------------------------------------------------- GEMM (m97)
// C[M][N] = A[M][K] @ Bt[N][K]^T + bias[N]; OB=1 -> bf16 out else f32
template <int OB>
__global__ __launch_bounds__(256) void gemm_bt(
    const u16* __restrict__ A, const u16* __restrict__ Bt,
    const float* __restrict__ bias, void* __restrict__ Cout,
    int M, int N, int K) {
  __shared__ __align__(16) u16 As[128 * 32];
  __shared__ __align__(16) u16 Bs[128 * 32];
  int tid = threadIdx.x;
  int wave = tid >> 6, lane = tid & 63, quad = lane >> 4, l16 = lane & 15;
  int wm = (wave >> 1) * 64, wn = (wave & 1) * 64;
  int m0 = blockIdx.y * 128, n0 = blockIdx.x * 128;
  f32x4 acc[4][4];
  for (int i = 0; i < 4; ++i)
    for (int j = 0; j < 4; ++j) acc[i][j] = (f32x4){0.f, 0.f, 0.f, 0.f};

  // staging: per call, lane -> row = lane>>2, colhalf = (lane&3)*8 (16B/lane)
  int srow = wave * 32 + (lane >> 2);
  int scol = (lane & 3) * 8;
  const u16* ag = A + (size_t)(m0 + srow) * K + scol;
  const u16* bg = Bt + (size_t)(n0 + srow) * K + scol;
  u16* al = As + wave * 32 * 32;
  u16* bl = Bs + wave * 32 * 32;

  for (int kk = 0; kk < K; kk += 32) {
    __syncthreads();
    gl_lds16(ag + kk, al);
    gl_lds16(ag + kk + (size_t)16 * K, al + 16 * 32);
    gl_lds16(bg + kk, bl);
    gl_lds16(bg + kk + (size_t)16 * K, bl + 16 * 32);
    __syncthreads();
    bf16x8 af[4], bfr[4];
    for (int i = 0; i < 4; ++i)
      af[i] = *(const bf16x8*)(As + (wm + i * 16 + l16) * 32 + quad * 8);
    for (int i = 0; i < 4; ++i)
      bfr[i] = *(const bf16x8*)(Bs + (wn + i * 16 + l16) * 32 + quad * 8);
    for (int mi = 0; mi < 4; ++mi)
      for (int ni = 0; ni < 4; ++ni)
        acc[mi][ni] = __builtin_amdgcn_mfma_f32_16x16x32_bf16(
            af[mi], bfr[ni], acc[mi][ni], 0, 0, 0);
  }
  for (int ni = 0; ni < 4; ++ni) {
    int col = n0 + wn + ni * 16 + l16;
    float bv = bias[col];
    for (int mi = 0; mi < 4; ++mi) {
      int row = m0 + wm + mi * 16 + quad * 4;
      for (int r = 0; r < 4; ++r) {
        float v = acc[mi][ni][r] + bv;
        if (OB)
          ((u16*)Cout)[(size_t)(row + r) * N + col] = f2bf(v);
        else
          ((float*)Cout)[(size_t)(row + r) * N + col] = v;
      }
    }
  }
}

// ---------------------------------------------------------------- attention
// Flash attention over compacted keys. Block = 4 waves; wave owns 32 q-rows
// (2 groups of 16). 64-key tiles. S^T formulation (C col = q = lane&15).
__global__ __launch_bounds__(256) void attn_kernel(
    const u16* __restrict__ qkv, const int* __restrict__ idx,
    const int* __restrict__ nbv, const u16* __restrict__ VTc,
    u16* __restrict__ aout) {
  const int S = 2048, TH = 1536, H = 512;
  int b = blockIdx.z, h = blockIdx.y, q0 = blockIdx.x * 128;
  int bh = b * 8 + h;
  int tid = threadIdx.x;
  int wave = tid >> 6, lane = tid & 63, quad = lane >> 4, l16 = lane & 15;
  int nb = nbv[b];
  int npad = (nb + 63) & ~63;

  __shared__ __align__(16) u16 Kt[64 * 72];
  __shared__ __align__(16) u16 Vt[64 * 72];
  __shared__ __align__(16) u16 Pw[4][32 * 72];

  // Q fragments (B-operand), pre-scaled by 1/8 (exact exponent shift)
  bf16x8 qf[2][2];
  for (int qg = 0; qg < 2; ++qg) {
    int qrow = b * S + q0 + wave * 32 + qg * 16 + l16;
    for (int half = 0; half < 2; ++half) {
      const us8 raw = *(const us8*)(qkv + (size_t)qrow * TH + h * 64 +
                                    half * 32 + quad * 8);
      bf16x8 t;
      for (int j = 0; j < 8; ++j) t[j] = bfbits(f2bf(bf2f(raw[j]) * 0.125f));
      qf[qg][half] = t;
    }
  }

  float m[2] = {-1e30f, -1e30f}, l[2] = {0.f, 0.f};
  f32x4 o[2][4];
  for (int qg = 0; qg < 2; ++qg)
    for (int c = 0; c < 4; ++c) o[qg][c] = (f32x4){0.f, 0.f, 0.f, 0.f};

  for (int kt0 = 0; kt0 < npad; kt0 += 64) {
    __syncthreads();
    for (int rep = 0; rep < 2; ++rep) {
      int id = rep * 256 + tid, j = id >> 3, c = id & 7;
      int src = idx[b * S + kt0 + j];
      us8 kv = *(const us8*)(qkv + (size_t)(b * S + src) * TH + 512 + h * 64 +
                             c * 8);
      *(us8*)(Kt + j * 72 + c * 8) = kv;
      us8 vv = *(const us8*)(VTc + ((size_t)bh * 64 + j) * 2048 + kt0 + c * 8);
      *(us8*)(Vt + j * 72 + c * 8) = vv;
    }
    __syncthreads();

    // S^T tiles: key = f*16 + quad*4 + r, qcol = l16 (per q-group)
    float s[2][16];
    for (int f = 0; f < 4; ++f) {
      bf16x8 k0 = *(const bf16x8*)(Kt + (f * 16 + l16) * 72 + quad * 8);
      bf16x8 k1 = *(const bf16x8*)(Kt + (f * 16 + l16) * 72 + 32 + quad * 8);
      for (int qg = 0; qg < 2; ++qg) {
        f32x4 sa = (f32x4){0.f, 0.f, 0.f, 0.f};
        sa = __builtin_amdgcn_mfma_f32_16x16x32_bf16(k0, qf[qg][0], sa, 0, 0, 0);
        sa = __builtin_amdgcn_mfma_f32_16x16x32_bf16(k1, qf[qg][1], sa, 0, 0, 0);
        for (int r = 0; r < 4; ++r) s[qg][f * 4 + r] = sa[r];
      }
    }
    if (kt0 + 64 > nb) {  // uniform: only the last tile has padded slots
      for (int f = 0; f < 4; ++f)
        for (int r = 0; r < 4; ++r) {
          int jg = kt0 + f * 16 + quad * 4 + r;
          if (jg >= nb) { s[0][f * 4 + r] = -1e30f; s[1][f * 4 + r] = -1e30f; }
        }
    }

    for (int qg = 0; qg < 2; ++qg) {
      float tmax = s[qg][0];
      for (int i = 1; i < 16; ++i) tmax = fmaxf(tmax, s[qg][i]);
      tmax = fmaxf(tmax, __shfl_xor(tmax, 16));
      tmax = fmaxf(tmax, __shfl_xor(tmax, 32));
      float m_new = fmaxf(m[qg], tmax);
      float alpha = __expf(m[qg] - m_new);
      float p[16], tsum = 0.f;
      for (int i = 0; i < 16; ++i) {
        p[i] = __expf(s[qg][i] - m_new);
        tsum += p[i];
      }
      tsum += __shfl_xor(tsum, 16);
      tsum += __shfl_xor(tsum, 32);
      l[qg] = l[qg] * alpha + tsum;
      m[qg] = m_new;
      for (int c = 0; c < 4; ++c)
        for (int r = 0; r < 4; ++r) o[qg][c][r] *= alpha;
      u16* pw = &Pw[wave][0];
      for (int f = 0; f < 4; ++f) {
        us4 pk;
        for (int r = 0; r < 4; ++r) pk[r] = f2bf(p[f * 4 + r]);
        *(us4*)(pw + (qg * 16 + l16) * 72 + f * 16 + quad * 4) = pk;
      }
    }

    // O^T += V^T * P^T ; V-frags shared across the two q-groups
    for (int c32 = 0; c32 < 2; ++c32) {
      bf16x8 vf[4];
      for (int dc = 0; dc < 4; ++dc)
        vf[dc] = *(const bf16x8*)(Vt + (dc * 16 + l16) * 72 + c32 * 32 +
                                  quad * 8);
      for (int qg = 0; qg < 2; ++qg) {
        bf16x8 pf = *(const bf16x8*)(&Pw[wave][0] + (qg * 16 + l16) * 72 +
                                     c32 * 32 + quad * 8);
        for (int dc = 0; dc < 4; ++dc)
          o[qg][dc] = __builtin_amdgcn_mfma_f32_16x16x32_bf16(vf[dc], pf,
                                                              o[qg][dc], 0, 0, 0);
      }
    }
  }

  for (int qg = 0; qg < 2; ++qg) {
    float inv = 1.f / l[qg];
    int qrow = b * S + q0 + wave * 32 + qg * 16 + l16;
    for (int dc = 0; dc < 4; ++dc) {
      us4 pk;
      for (int r = 0; r < 4; ++r) pk[r] = f2bf(o[qg][dc][r] * inv);
      *(us4*)(aout + (size_t)qrow * H + h * 64 + dc * 16 + quad * 4) = pk;
    }
  }
}

// ---------------------------------------------------------------- launch
extern "C" void kernel_launch(void* const* d_in, const int* in_sizes, int n_in,
                              void* d_out, int out_size, void* d_ws,
                              size_t ws_size, hipStream_t stream) {
  const float* x = (const float*)d_in[0];     // [4,2048,512]
  const int* mask = (const int*)d_in[1];      // [4,2048]
  const float* Wc = (const float*)d_in[2];    // [512,1536]
  const float* bc = (const float*)d_in[3];    // [1536]
  const float* Wo = (const float*)d_in[4];    // [512,512]
  const float* bo = (const float*)d_in[5];    // [512]
  float* out = (float*)d_out;                 // [4,2048,512] fp32

  char* ws = (char*)d_ws;
  u16* xbf  = (u16*)(ws);                     //  8 MB: x bf16 (aliased by aout)
  u16* wct  = (u16*)(ws + 8388608);           //  1.5 MB
  u16* wot  = (u16*)(ws + 9961472);           //  0.5 MB
  u16* qkv  = (u16*)(ws + 10485760);          // 24 MB
  u16* vtc  = (u16*)(ws + 35651584);          //  8 MB: compacted V^T
  int* idx  = (int*)(ws + 44040192);          // 32 KB
  int* nbv  = (int*)(ws + 44072960);          // 16 B
  u16* aout = xbf;                            // reuse (xbf dead after gemm1)

  f32_to_bf16_vec<<<4096, 256, 0, stream>>>(x, xbf);
  transpose_bf16<<<dim3(48, 16), dim3(32, 8), 0, stream>>>(Wc, wct, 512, 1536);
  transpose_bf16<<<dim3(16, 16), dim3(32, 8), 0, stream>>>(Wo, wot, 512, 512);
  compact_mask<<<4, 256, 0, stream>>>(mask, idx, nbv);
  gemm_bt<1><<<dim3(12, 64), 256, 0, stream>>>(xbf, wct, bc, qkv, 8192, 1536, 512);
  build_vt<<<dim3(32, 4), 256, 0, stream>>>(qkv, idx, nbv, vtc);
  attn_kernel<<<dim3(16, 8, 4), 256, 0, stream>>>(qkv, idx, nbv, vtc, aout);
  gemm_bt<0><<<dim3(4, 64), 256, 0, stream>>>(aout, wot, bo, out, 8192, 512, 512);
}

// Round 3
// 179.524 us; speedup vs baseline: 1.2513x; 1.0099x over previous
//
#include <hip/hip_runtime.h>
#include <hip/hip_bf16.h>
#include <stdint.h>

typedef unsigned short u16;
typedef __attribute__((ext_vector_type(8))) __bf16 bf16x8;
typedef __attribute__((ext_vector_type(8))) unsigned short us8;
typedef __attribute__((ext_vector_type(4))) unsigned short us4;
typedef __attribute__((ext_vector_type(4))) float f32x4;

#define KSCALE_Q 0.18033688011112042f  /* (1/8) * log2(e) */

__device__ inline u16 f2bf(float f) {
  union { __bf16 b; u16 s; } x; x.b = (__bf16)f; return x.s;
}
__device__ __forceinline__ void gl_lds16(const u16* g, u16* l) {
  __builtin_amdgcn_global_load_lds(
      (const __attribute__((address_space(1))) void*)g,
      (__attribute__((address_space(3))) void*)l, 16, 0, 0);
}

// ---------------------------------------------------------------- prep (fused)
// blocks [0,4096): x->bf16 ; [4096,4864): Wc^T ; [4864,5120): Wo^T ;
// [5120,5124): mask compaction (idx, nbv)
__global__ __launch_bounds__(256) void prep(
    const float* __restrict__ x, const float* __restrict__ Wc,
    const float* __restrict__ Wo, const int* __restrict__ mask,
    u16* __restrict__ xbf, u16* __restrict__ wct, u16* __restrict__ wot,
    int* __restrict__ idx, int* __restrict__ nbv) {
  int r = blockIdx.x, tid = threadIdx.x;
  if (r < 4096) {
    int i = r * 256 + tid;
    float4 v = ((const float4*)x)[i];
    us4 o;
    o[0] = f2bf(v.x); o[1] = f2bf(v.y); o[2] = f2bf(v.z); o[3] = f2bf(v.w);
    ((us4*)xbf)[i] = o;
    return;
  }
  __shared__ float tile[32][33];
  __shared__ int ps[256];
  if (r < 5120) {
    const float* in; u16* outT; int R, C, bi;
    if (r < 4864) { in = Wc; outT = wct; R = 512; C = 1536; bi = r - 4096; }
    else          { in = Wo; outT = wot; R = 512; C = 512;  bi = r - 4864; }
    int nbx = C >> 5;
    int bx = bi % nbx, by = bi / nbx;
    int xq = tid & 31, yq = tid >> 5;
    int c0 = bx * 32, r0 = by * 32;
    for (int j = 0; j < 32; j += 8)
      tile[yq + j][xq] = in[(size_t)(r0 + yq + j) * C + c0 + xq];
    __syncthreads();
    for (int j = 0; j < 32; j += 8)
      outT[(size_t)(c0 + yq + j) * R + r0 + xq] = f2bf(tile[xq][yq + j]);
    return;
  }
  int b = r - 5120;
  const int* mrow = mask + b * 2048;
  int4 a = ((const int4*)mrow)[tid * 2];
  int4 c = ((const int4*)mrow)[tid * 2 + 1];
  int v[8] = {a.x, a.y, a.z, a.w, c.x, c.y, c.z, c.w};
  int cnt = 0;
  for (int i = 0; i < 8; ++i) cnt += (v[i] > 0);
  ps[tid] = cnt;
  __syncthreads();
  for (int off = 1; off < 256; off <<= 1) {
    int xv = ps[tid];
    int yv = (tid >= off) ? ps[tid - off] : 0;
    __syncthreads();
    ps[tid] = xv + yv;
    __syncthreads();
  }
  int total = ps[255];
  int pos = ps[tid] - cnt;
  int* ip = idx + b * 2048;
  for (int i = 0; i < 8; ++i)
    if (v[i] > 0) ip[pos++] = tid * 8 + i;
  for (int i = 0; i < 8; ++i) {
    int j = tid * 8 + i;
    if (j >= total) ip[j] = 0;
  }
  if (tid == 0) nbv[b] = total;
}

// ---------------------------------------------------------------- GEMM 128x64
// C = A @ Bt^T + bias, scaled by oscale. Swizzled global_load_lds staging.
// GATHER: A rows taken from idx[b*2048 + m0+row]; C rows offset by b*2048.
template <int OB, int GATHER>
__global__ __launch_bounds__(256) void gemm64(
    const u16* __restrict__ A, const u16* __restrict__ Bt,
    const float* __restrict__ bias, void* __restrict__ Cout,
    const int* __restrict__ idx, const int* __restrict__ nbv,
    int N, int K, float oscale) {
  int b = GATHER ? blockIdx.z : 0;
  int m0 = blockIdx.y * 128, n0 = blockIdx.x * 64;
  if (GATHER) {
    int npad = (nbv[b] + 63) & ~63;
    if (m0 >= npad) return;
  }
  __shared__ __align__(16) u16 As[128 * 32];
  __shared__ __align__(16) u16 Bs[64 * 32];
  int tid = threadIdx.x, wave = tid >> 6, lane = tid & 63;
  int quad = lane >> 4, l16 = lane & 15;
  int wm = (wave >> 1) * 64, wn = (wave & 1) * 32;

  // staging: content 16B-block cb = (lane&3) ^ ((row>>1)&3), LDS lane-linear
  int arow0 = wave * 32 + (lane >> 2);
  int acb = (lane & 3) ^ ((lane >> 3) & 3);
  const u16 *ag0, *ag1;
  if (GATHER) {
    int g0 = idx[b * 2048 + m0 + arow0];
    int g1 = idx[b * 2048 + m0 + arow0 + 16];
    ag0 = A + ((size_t)(b * 2048 + g0)) * K + acb * 8;
    ag1 = A + ((size_t)(b * 2048 + g1)) * K + acb * 8;
  } else {
    ag0 = A + (size_t)(m0 + arow0) * K + acb * 8;
    ag1 = ag0 + (size_t)16 * K;
  }
  u16* al0 = As + wave * 32 * 32;
  u16* al1 = al0 + 16 * 32;
  int brow = wave * 16 + (lane >> 2);
  const u16* bg = Bt + (size_t)(n0 + brow) * K + acb * 8;
  u16* bl = Bs + wave * 16 * 32;

  f32x4 acc[4][2];
  for (int i = 0; i < 4; ++i)
    for (int j = 0; j < 2; ++j) acc[i][j] = (f32x4){0.f, 0.f, 0.f, 0.f};

  int swz = (l16 >> 1) & 3;
  for (int kk = 0; kk < K; kk += 32) {
    __syncthreads();
    gl_lds16(ag0 + kk, al0);
    gl_lds16(ag1 + kk, al1);
    gl_lds16(bg + kk, bl);
    __syncthreads();
    bf16x8 af[4], bfr[2];
    for (int i = 0; i < 4; ++i)
      af[i] = *(const bf16x8*)(As + (wm + i * 16 + l16) * 32 +
                               (quad ^ swz) * 8);
    for (int j = 0; j < 2; ++j)
      bfr[j] = *(const bf16x8*)(Bs + (wn + j * 16 + l16) * 32 +
                                (quad ^ swz) * 8);
    for (int i = 0; i < 4; ++i)
      for (int j = 0; j < 2; ++j)
        acc[i][j] = __builtin_amdgcn_mfma_f32_16x16x32_bf16(
            af[i], bfr[j], acc[i][j], 0, 0, 0);
  }
  for (int j = 0; j < 2; ++j) {
    int col = n0 + wn + j * 16 + l16;
    float bv = bias[col];
    for (int i = 0; i < 4; ++i) {
      int rowb = m0 + wm + i * 16 + quad * 4;
      for (int rr = 0; rr < 4; ++rr) {
        float v = (acc[i][j][rr] + bv) * oscale;
        size_t row = (GATHER ? (size_t)b * 2048 : (size_t)0) + rowb + rr;
        if (OB)
          ((u16*)Cout)[row * N + col] = f2bf(v);
        else
          ((float*)Cout)[row * N + col] = v;
      }
    }
  }
}

// ---------------------------------------------------------------- V^T build
// VTc[b][h][d][j] = KVc[b*2048+j][512 + h*64 + d], j < npad
__global__ __launch_bounds__(256) void build_vt(
    const u16* __restrict__ KVc, const int* __restrict__ nbv,
    u16* __restrict__ VTc) {
  int b = blockIdx.y, j0 = blockIdx.x * 64, tid = threadIdx.x;
  int npad = (nbv[b] + 63) & ~63;
  if (j0 >= npad) return;
  __shared__ __align__(16) u16 Vl[64 * 72];
  for (int h = 0; h < 8; ++h) {
    __syncthreads();
    for (int rep = 0; rep < 2; ++rep) {
      int id = rep * 256 + tid, j = id >> 3, c = id & 7;
      us8 vv = *(const us8*)(KVc + ((size_t)(b * 2048 + j0 + j)) * 1024 + 512 +
                             h * 64 + c * 8);
      *(us8*)(Vl + j * 72 + c * 8) = vv;
    }
    __syncthreads();
    for (int rep = 0; rep < 2; ++rep) {
      int id = rep * 256 + tid, d = id >> 3, c = id & 7;
      us8 o;
      for (int i = 0; i < 8; ++i) o[i] = Vl[(c * 8 + i) * 72 + d];
      *(us8*)(VTc + ((size_t)(b * 8 + h) * 64 + d) * 2048 + j0 + c * 8) = o;
    }
  }
}

// ---------------------------------------------------------------- attention
// Flash over compacted keys; no-max softmax in exp2 domain (Q pre-scaled by
// log2e/8 in gemm_q). Wave = 32 q-rows (2 groups), 64-key tiles.
__global__ __launch_bounds__(256) void attn_kernel(
    const u16* __restrict__ Qc, const u16* __restrict__ KVc,
    const u16* __restrict__ VTc, const int* __restrict__ nbv,
    u16* __restrict__ aout) {
  const int S = 2048;
  int b = blockIdx.z, h = blockIdx.y, q0 = blockIdx.x * 128;
  int bh = b * 8 + h;
  int tid = threadIdx.x, wave = tid >> 6, lane = tid & 63;
  int quad = lane >> 4, l16 = lane & 15;
  int nb = nbv[b];
  int npad = (nb + 63) & ~63;

  __shared__ __align__(16) u16 Kt[64 * 64];  // [key][d], swizzled 16B blocks
  __shared__ __align__(16) u16 Vt[64 * 64];  // [d][key], swizzled 16B blocks
  __shared__ __align__(16) u16 Pw[4][32 * 72];

  bf16x8 qf[2][2];
  for (int qg = 0; qg < 2; ++qg) {
    int qrow = b * S + q0 + wave * 32 + qg * 16 + l16;
    for (int half = 0; half < 2; ++half)
      qf[qg][half] = *(const bf16x8*)(Qc + (size_t)qrow * 512 + h * 64 +
                                      half * 32 + quad * 8);
  }

  float l[2] = {0.f, 0.f};
  f32x4 o[2][4];
  for (int qg = 0; qg < 2; ++qg)
    for (int c = 0; c < 4; ++c) o[qg][c] = (f32x4){0.f, 0.f, 0.f, 0.f};

  // staging: 8 rows/instr (128 B rows); content cb = (lane&7) ^ (lane>>3)
  int jrow = lane >> 3, slot = lane & 7;
  int kcb = slot ^ jrow;
  int kr0 = wave * 16 + jrow;
  const u16* kg = KVc + ((size_t)(b * 2048) + kr0) * 1024 + h * 64 + kcb * 8;
  const u16* vg = VTc + ((size_t)(bh * 64) + kr0) * 2048 + kcb * 8;
  u16* kl = Kt + wave * 16 * 64;
  u16* vl = Vt + wave * 16 * 64;
  int swz7 = l16 & 7;

  for (int kt0 = 0; kt0 < npad; kt0 += 64) {
    __syncthreads();
    gl_lds16(kg, kl);
    gl_lds16(kg + (size_t)8 * 1024, kl + 8 * 64);
    gl_lds16(vg, vl);
    gl_lds16(vg + (size_t)8 * 2048, vl + 8 * 64);
    kg += (size_t)64 * 1024;
    vg += 64;
    __syncthreads();

    float p[2][16];
    for (int f = 0; f < 4; ++f) {
      int krow = f * 16 + l16;
      int c0 = (quad ^ swz7) * 8;
      bf16x8 k0 = *(const bf16x8*)(Kt + krow * 64 + c0);
      bf16x8 k1 = *(const bf16x8*)(Kt + krow * 64 + (c0 ^ 32));
      for (int qg = 0; qg < 2; ++qg) {
        f32x4 sa = (f32x4){0.f, 0.f, 0.f, 0.f};
        sa = __builtin_amdgcn_mfma_f32_16x16x32_bf16(k0, qf[qg][0], sa, 0, 0, 0);
        sa = __builtin_amdgcn_mfma_f32_16x16x32_bf16(k1, qf[qg][1], sa, 0, 0, 0);
        for (int r = 0; r < 4; ++r) p[qg][f * 4 + r] = sa[r];
      }
    }
    if (kt0 + 64 > nb) {  // only the final tile has padded key slots
      for (int f = 0; f < 4; ++f)
        for (int r = 0; r < 4; ++r) {
          int jg = kt0 + f * 16 + quad * 4 + r;
          if (jg >= nb) { p[0][f * 4 + r] = -1e30f; p[1][f * 4 + r] = -1e30f; }
        }
    }
    for (int qg = 0; qg < 2; ++qg) {
      u16* pw = &Pw[wave][0] + (qg * 16 + l16) * 72;
      float ts = 0.f;
      for (int f = 0; f < 4; ++f) {
        us4 pk;
        for (int r = 0; r < 4; ++r) {
          float e = exp2f(p[qg][f * 4 + r]);
          ts += e;
          pk[r] = f2bf(e);
        }
        *(us4*)(pw + f * 16 + quad * 4) = pk;
      }
      l[qg] += ts;
    }
    for (int c32 = 0; c32 < 2; ++c32) {
      bf16x8 vf[4];
      for (int dc = 0; dc < 4; ++dc)
        vf[dc] = *(const bf16x8*)(Vt + (dc * 16 + l16) * 64 +
                                  ((quad ^ swz7) ^ (c32 << 2)) * 8);
      for (int qg = 0; qg < 2; ++qg) {
        bf16x8 pf = *(const bf16x8*)(&Pw[wave][0] + (qg * 16 + l16) * 72 +
                                     c32 * 32 + quad * 8);
        for (int dc = 0; dc < 4; ++dc)
          o[qg][dc] = __builtin_amdgcn_mfma_f32_16x16x32_bf16(
              vf[dc], pf, o[qg][dc], 0, 0, 0);
      }
    }
  }

  for (int qg = 0; qg < 2; ++qg) {
    float lt = l[qg];
    lt += __shfl_xor(lt, 16);
    lt += __shfl_xor(lt, 32);
    float inv = 1.f / lt;
    int qrow = b * S + q0 + wave * 32 + qg * 16 + l16;
    for (int dc = 0; dc < 4; ++dc) {
      us4 pk;
      for (int r = 0; r < 4; ++r) pk[r] = f2bf(o[qg][dc][r] * inv);
      *(us4*)(aout + (size_t)qrow * 512 + h * 64 + dc * 16 + quad * 4) = pk;
    }
  }
}

// ---------------------------------------------------------------- launch
extern "C" void kernel_launch(void* const* d_in, const int* in_sizes, int n_in,
                              void* d_out, int out_size, void* d_ws,
                              size_t ws_size, hipStream_t stream) {
  const float* x = (const float*)d_in[0];     // [4,2048,512]
  const int* mask = (const int*)d_in[1];      // [4,2048]
  const float* Wc = (const float*)d_in[2];    // [512,1536]
  const float* bc = (const float*)d_in[3];    // [1536]
  const float* Wo = (const float*)d_in[4];    // [512,512]
  const float* bo = (const float*)d_in[5];    // [512]
  float* out = (float*)d_out;                 // [4,2048,512] fp32

  char* ws = (char*)d_ws;
  u16* xbf = (u16*)(ws);                      //  8 MB [8192][512]
  u16* wct = (u16*)(ws + 8388608);            //  1.5 MB [1536][512]
  u16* wot = (u16*)(ws + 9961472);            //  0.5 MB [512][512]
  u16* Qc  = (u16*)(ws + 10485760);           //  8 MB [8192][512] (pre-scaled)
  u16* KVc = (u16*)(ws + 18874368);           // 16 MB [4*2048][1024]
  u16* vtc = (u16*)(ws + 35651584);           //  8 MB [32][64][2048]
  int* idx = (int*)(ws + 44040192);           // 32 KB
  int* nbv = (int*)(ws + 44072960);           // 16 B
  u16* aout = xbf;                            // reuse (xbf dead after gemms)

  prep<<<5124, 256, 0, stream>>>(x, Wc, Wo, mask, xbf, wct, wot, idx, nbv);
  gemm64<1, 0><<<dim3(8, 64), 256, 0, stream>>>(
      xbf, wct, bc, Qc, nullptr, nullptr, 512, 512, KSCALE_Q);
  gemm64<1, 1><<<dim3(16, 16, 4), 256, 0, stream>>>(
      xbf, wct + (size_t)512 * 512, bc + 512, KVc, idx, nbv, 1024, 512, 1.0f);
  build_vt<<<dim3(32, 4), 256, 0, stream>>>(KVc, nbv, vtc);
  attn_kernel<<<dim3(16, 8, 4), 256, 0, stream>>>(Qc, KVc, vtc, nbv, aout);
  gemm64<0, 0><<<dim3(8, 64), 256, 0, stream>>>(
      aout, wot, bo, out, nullptr, nullptr, 512, 512, 1.0f);
}

// Round 4
// 168.386 us; speedup vs baseline: 1.3341x; 1.0661x over previous
//
#include <hip/hip_runtime.h>
#include <hip/hip_bf16.h>
#include <stdint.h>

typedef unsigned short u16;
typedef __attribute__((ext_vector_type(8))) __bf16 bf16x8;
typedef __attribute__((ext_vector_type(8))) unsigned short us8;
typedef __attribute__((ext_vector_type(4))) unsigned short us4;
typedef __attribute__((ext_vector_type(4))) float f32x4;
typedef __attribute__((ext_vector_type(16))) float f32x16;

#define KSCALE_Q 0.18033688011112042f  /* (1/8) * log2(e) */

__device__ inline u16 f2bf(float f) {
  union { __bf16 b; u16 s; } x; x.b = (__bf16)f; return x.s;
}
__device__ inline f32x16 zero16() {
  f32x16 z; for (int i = 0; i < 16; ++i) z[i] = 0.f; return z;
}
__device__ __forceinline__ void gl_lds16(const u16* g, u16* l) {
  __builtin_amdgcn_global_load_lds(
      (const __attribute__((address_space(1))) void*)g,
      (__attribute__((address_space(3))) void*)l, 16, 0, 0);
}

// ---------------------------------------------------------------- prep (fused)
__global__ __launch_bounds__(256) void prep(
    const float* __restrict__ x, const float* __restrict__ Wc,
    const float* __restrict__ Wo, const int* __restrict__ mask,
    u16* __restrict__ xbf, u16* __restrict__ wct, u16* __restrict__ wot,
    int* __restrict__ idx, int* __restrict__ nbv) {
  int r = blockIdx.x, tid = threadIdx.x;
  if (r < 4096) {
    int i = r * 256 + tid;
    float4 v = ((const float4*)x)[i];
    us4 o;
    o[0] = f2bf(v.x); o[1] = f2bf(v.y); o[2] = f2bf(v.z); o[3] = f2bf(v.w);
    ((us4*)xbf)[i] = o;
    return;
  }
  __shared__ float tile[32][33];
  __shared__ int ps[256];
  if (r < 5120) {
    const float* in; u16* outT; int R, C, bi;
    if (r < 4864) { in = Wc; outT = wct; R = 512; C = 1536; bi = r - 4096; }
    else          { in = Wo; outT = wot; R = 512; C = 512;  bi = r - 4864; }
    int nbx = C >> 5;
    int bx = bi % nbx, by = bi / nbx;
    int xq = tid & 31, yq = tid >> 5;
    int c0 = bx * 32, r0 = by * 32;
    for (int j = 0; j < 32; j += 8)
      tile[yq + j][xq] = in[(size_t)(r0 + yq + j) * C + c0 + xq];
    __syncthreads();
    for (int j = 0; j < 32; j += 8)
      outT[(size_t)(c0 + yq + j) * R + r0 + xq] = f2bf(tile[xq][yq + j]);
    return;
  }
  int b = r - 5120;
  const int* mrow = mask + b * 2048;
  int4 a = ((const int4*)mrow)[tid * 2];
  int4 c = ((const int4*)mrow)[tid * 2 + 1];
  int v[8] = {a.x, a.y, a.z, a.w, c.x, c.y, c.z, c.w};
  int cnt = 0;
  for (int i = 0; i < 8; ++i) cnt += (v[i] > 0);
  ps[tid] = cnt;
  __syncthreads();
  for (int off = 1; off < 256; off <<= 1) {
    int xv = ps[tid];
    int yv = (tid >= off) ? ps[tid - off] : 0;
    __syncthreads();
    ps[tid] = xv + yv;
    __syncthreads();
  }
  int total = ps[255];
  int pos = ps[tid] - cnt;
  int* ip = idx + b * 2048;
  for (int i = 0; i < 8; ++i)
    if (v[i] > 0) ip[pos++] = tid * 8 + i;
  for (int i = 0; i < 8; ++i) {
    int j = tid * 8 + i;
    if (j >= total) ip[j] = 0;
  }
  if (tid == 0) nbv[b] = total;
}

// ---------------------------------------------------------------- GEMM 128x64
template <int OB>
__global__ __launch_bounds__(256) void gemm64(
    const u16* __restrict__ A, const u16* __restrict__ Bt,
    const float* __restrict__ bias, void* __restrict__ Cout,
    int N, int K, float oscale) {
  int m0 = blockIdx.y * 128, n0 = blockIdx.x * 64;
  __shared__ __align__(16) u16 As[128 * 32];
  __shared__ __align__(16) u16 Bs[64 * 32];
  int tid = threadIdx.x, wave = tid >> 6, lane = tid & 63;
  int quad = lane >> 4, l16 = lane & 15;
  int wm = (wave >> 1) * 64, wn = (wave & 1) * 32;

  int arow0 = wave * 32 + (lane >> 2);
  int acb = (lane & 3) ^ ((lane >> 3) & 3);
  const u16* ag0 = A + (size_t)(m0 + arow0) * K + acb * 8;
  const u16* ag1 = ag0 + (size_t)16 * K;
  u16* al0 = As + wave * 32 * 32;
  u16* al1 = al0 + 16 * 32;
  int brow = wave * 16 + (lane >> 2);
  const u16* bg = Bt + (size_t)(n0 + brow) * K + acb * 8;
  u16* bl = Bs + wave * 16 * 32;

  f32x4 acc[4][2];
  for (int i = 0; i < 4; ++i)
    for (int j = 0; j < 2; ++j) acc[i][j] = (f32x4){0.f, 0.f, 0.f, 0.f};

  int swz = (l16 >> 1) & 3;
  for (int kk = 0; kk < K; kk += 32) {
    __syncthreads();
    gl_lds16(ag0 + kk, al0);
    gl_lds16(ag1 + kk, al1);
    gl_lds16(bg + kk, bl);
    __syncthreads();
    bf16x8 af[4], bfr[2];
    for (int i = 0; i < 4; ++i)
      af[i] = *(const bf16x8*)(As + (wm + i * 16 + l16) * 32 +
                               (quad ^ swz) * 8);
    for (int j = 0; j < 2; ++j)
      bfr[j] = *(const bf16x8*)(Bs + (wn + j * 16 + l16) * 32 +
                                (quad ^ swz) * 8);
    for (int i = 0; i < 4; ++i)
      for (int j = 0; j < 2; ++j)
        acc[i][j] = __builtin_amdgcn_mfma_f32_16x16x32_bf16(
            af[i], bfr[j], acc[i][j], 0, 0, 0);
  }
  for (int j = 0; j < 2; ++j) {
    int col = n0 + wn + j * 16 + l16;
    float bv = bias[col];
    for (int i = 0; i < 4; ++i) {
      int rowb = m0 + wm + i * 16 + quad * 4;
      for (int rr = 0; rr < 4; ++rr) {
        float v = (acc[i][j][rr] + bv) * oscale;
        if (OB)
          ((u16*)Cout)[(size_t)(rowb + rr) * N + col] = f2bf(v);
        else
          ((float*)Cout)[(size_t)(rowb + rr) * N + col] = v;
      }
    }
  }
}

// ---------------------------------------------------------------- KV GEMM
// Gathered rows (compact keys). cols 0..511 -> Kc[b*2048+key][512] (bf16);
// cols 512..1023 -> V, written TRANSPOSED into VTc[(b*8+h)*64+d][2048] at [key].
__global__ __launch_bounds__(256) void gemm_kv(
    const u16* __restrict__ A, const u16* __restrict__ Bt,
    const float* __restrict__ bias, u16* __restrict__ Kc,
    u16* __restrict__ VTc, const int* __restrict__ idx,
    const int* __restrict__ nbv) {
  const int K = 512, N = 1024;
  int b = blockIdx.z;
  int m0 = blockIdx.y * 128, n0 = blockIdx.x * 64;
  int npad = (nbv[b] + 127) & ~127;
  if (m0 >= npad) return;
  __shared__ __align__(16) u16 As[128 * 32];
  __shared__ __align__(16) u16 Bs[64 * 32];
  int tid = threadIdx.x, wave = tid >> 6, lane = tid & 63;
  int quad = lane >> 4, l16 = lane & 15;
  int wm = (wave >> 1) * 64, wn = (wave & 1) * 32;

  int arow0 = wave * 32 + (lane >> 2);
  int acb = (lane & 3) ^ ((lane >> 3) & 3);
  int g0 = idx[b * 2048 + m0 + arow0];
  int g1 = idx[b * 2048 + m0 + arow0 + 16];
  const u16* ag0 = A + ((size_t)(b * 2048 + g0)) * K + acb * 8;
  const u16* ag1 = A + ((size_t)(b * 2048 + g1)) * K + acb * 8;
  u16* al0 = As + wave * 32 * 32;
  u16* al1 = al0 + 16 * 32;
  int brow = wave * 16 + (lane >> 2);
  const u16* bg = Bt + (size_t)(n0 + brow) * K + acb * 8;
  u16* bl = Bs + wave * 16 * 32;

  f32x4 acc[4][2];
  for (int i = 0; i < 4; ++i)
    for (int j = 0; j < 2; ++j) acc[i][j] = (f32x4){0.f, 0.f, 0.f, 0.f};

  int swz = (l16 >> 1) & 3;
  for (int kk = 0; kk < K; kk += 32) {
    __syncthreads();
    gl_lds16(ag0 + kk, al0);
    gl_lds16(ag1 + kk, al1);
    gl_lds16(bg + kk, bl);
    __syncthreads();
    bf16x8 af[4], bfr[2];
    for (int i = 0; i < 4; ++i)
      af[i] = *(const bf16x8*)(As + (wm + i * 16 + l16) * 32 +
                               (quad ^ swz) * 8);
    for (int j = 0; j < 2; ++j)
      bfr[j] = *(const bf16x8*)(Bs + (wn + j * 16 + l16) * 32 +
                                (quad ^ swz) * 8);
    for (int i = 0; i < 4; ++i)
      for (int j = 0; j < 2; ++j)
        acc[i][j] = __builtin_amdgcn_mfma_f32_16x16x32_bf16(
            af[i], bfr[j], acc[i][j], 0, 0, 0);
  }
  for (int j = 0; j < 2; ++j) {
    int col = n0 + wn + j * 16 + l16;
    float bv = bias[col];
    if (col < 512) {  // K half (uniform per j)
      for (int i = 0; i < 4; ++i) {
        int key0 = m0 + wm + i * 16 + quad * 4;
        for (int rr = 0; rr < 4; ++rr)
          Kc[((size_t)b * 2048 + key0 + rr) * 512 + col] =
              f2bf(acc[i][j][rr] + bv);
      }
    } else {  // V half -> transposed us4 along key dim
      int hd = col - 512;
      int h = hd >> 6, d = hd & 63;
      u16* vrow = VTc + ((size_t)(b * 8 + h) * 64 + d) * 2048;
      for (int i = 0; i < 4; ++i) {
        int key0 = m0 + wm + i * 16 + quad * 4;
        us4 pk;
        for (int rr = 0; rr < 4; ++rr) pk[rr] = f2bf(acc[i][j][rr] + bv);
        *(us4*)(vrow + key0) = pk;
      }
    }
  }
}

// ---------------------------------------------------------------- attention
// 32x32x16 MFMA flash. Wave = 32 q (q = lane&31); 128-key tiles.
// S^T = K.Q^T : C col = q (one q per lane!), row = key. No-max exp2 softmax.
__global__ __launch_bounds__(256) void attn_kernel(
    const u16* __restrict__ Qc, const u16* __restrict__ Kc,
    const u16* __restrict__ VTc, const int* __restrict__ nbv,
    u16* __restrict__ aout) {
  int b = blockIdx.z, h = blockIdx.y, q0 = blockIdx.x * 128;
  int bh = b * 8 + h;
  int tid = threadIdx.x, wave = tid >> 6, lane = tid & 63;
  int l5 = lane & 31, hi = lane >> 5;
  int nb = nbv[b];
  int npad = (nb + 127) & ~127;

  __shared__ __align__(16) u16 Kt[128 * 64];   // [key][d] swizzled 16B blocks
  __shared__ __align__(16) u16 Vt[64 * 128];   // [d][key] swizzled 16B blocks
  __shared__ __align__(16) u16 Pw[4][32 * 136];// per-wave P[q][key]

  int qrow = b * 2048 + q0 + wave * 32 + l5;
  bf16x8 qf[4];  // B-operand: k-dim d = s*16 + hi*8 + j, n = q = l5
  for (int s = 0; s < 4; ++s)
    qf[s] = *(const bf16x8*)(Qc + (size_t)qrow * 512 + h * 64 + s * 16 + hi * 8);

  f32x16 o[2];
  o[0] = zero16(); o[1] = zero16();
  float lsum = 0.f;

  // staging: Kt rows 128B (8 rows/instr, 4 instrs/wave), Vt rows 256B (4/instr)
  int krr = lane >> 3;                       // K: row within 8-group
  int kcb = (lane & 7) ^ krr;                // content 16B-block
  const u16* kg = Kc + ((size_t)(b * 2048) + wave * 32 + krr) * 512 + h * 64 +
                  kcb * 8;
  u16* kl = Kt + (wave * 32) * 64 + lane * 8;
  int vrr = lane >> 4;                       // V: row within 4-group
  const u16* vg = VTc + ((size_t)(bh * 64) + wave * 16 + vrr) * 2048;
  u16* vl = Vt + (wave * 16) * 128 + lane * 8;

  u16* pw = &Pw[wave][0] + l5 * 136;

  for (int kt0 = 0; kt0 < npad; kt0 += 128) {
    __syncthreads();
    for (int i = 0; i < 4; ++i)
      gl_lds16(kg + (size_t)(kt0 + i * 8) * 512, kl + i * 8 * 64);
    for (int i = 0; i < 4; ++i) {
      int vcb = (lane & 15) ^ ((i * 4 + vrr) & 7);
      gl_lds16(vg + (size_t)(i * 4) * 2048 + kt0 + vcb * 8, vl + i * 4 * 128);
    }
    __syncthreads();

    // QK^T: 4 key-groups of 32; write P as we go
    for (int kg4 = 0; kg4 < 4; ++kg4) {
      int krow = kg4 * 32 + l5;
      const u16* kro = Kt + krow * 64;
      int rx = krow & 7;
      f32x16 sa = zero16();
      for (int s = 0; s < 4; ++s) {
        bf16x8 ka = *(const bf16x8*)(kro + ((s * 2 + hi) ^ rx) * 8);
        sa = __builtin_amdgcn_mfma_f32_32x32x16_bf16(ka, qf[s], sa, 0, 0, 0);
      }
      if (kt0 + 128 > nb) {  // uniform branch: only final tile masks
        for (int r = 0; r < 16; ++r) {
          int jg = kt0 + kg4 * 32 + (r & 3) + 8 * (r >> 2) + 4 * hi;
          if (jg >= nb) sa[r] = -1e30f;
        }
      }
      for (int mI = 0; mI < 4; ++mI) {
        us4 pk;
        for (int r = 0; r < 4; ++r) {
          float e = exp2f(sa[mI * 4 + r]);
          lsum += e;
          pk[r] = f2bf(e);
        }
        *(us4*)(pw + kg4 * 32 + mI * 8 + hi * 4) = pk;
      }
    }

    // O^T += V^T . P^T  (A = V^T frag, B = P^T frag; no barrier: Pw wave-private)
    for (int kh = 0; kh < 2; ++kh)
      for (int t = 0; t < 4; ++t) {
        bf16x8 pb = *(const bf16x8*)(pw + kh * 64 + t * 16 + hi * 8);
        for (int dc = 0; dc < 2; ++dc) {
          int vrow = dc * 32 + l5;
          bf16x8 va = *(const bf16x8*)(
              Vt + vrow * 128 + ((kh * 8 + t * 2 + hi) ^ (vrow & 7)) * 8);
          o[dc] = __builtin_amdgcn_mfma_f32_32x32x16_bf16(va, pb, o[dc], 0, 0, 0);
        }
      }
  }

  lsum += __shfl_xor(lsum, 32);
  float inv = 1.f / lsum;
  for (int dc = 0; dc < 2; ++dc)
    for (int mI = 0; mI < 4; ++mI) {
      us4 pk;
      for (int r = 0; r < 4; ++r) pk[r] = f2bf(o[dc][mI * 4 + r] * inv);
      *(us4*)(aout + (size_t)qrow * 512 + h * 64 + dc * 32 + mI * 8 + hi * 4) =
          pk;
    }
}

// ---------------------------------------------------------------- launch
extern "C" void kernel_launch(void* const* d_in, const int* in_sizes, int n_in,
                              void* d_out, int out_size, void* d_ws,
                              size_t ws_size, hipStream_t stream) {
  const float* x = (const float*)d_in[0];     // [4,2048,512]
  const int* mask = (const int*)d_in[1];      // [4,2048]
  const float* Wc = (const float*)d_in[2];    // [512,1536]
  const float* bc = (const float*)d_in[3];    // [1536]
  const float* Wo = (const float*)d_in[4];    // [512,512]
  const float* bo = (const float*)d_in[5];    // [512]
  float* out = (float*)d_out;                 // [4,2048,512] fp32

  char* ws = (char*)d_ws;
  u16* xbf = (u16*)(ws);                      //  8 MB [8192][512]
  u16* wct = (u16*)(ws + 8388608);            //  1.5 MB [1536][512]
  u16* wot = (u16*)(ws + 9961472);            //  0.5 MB [512][512]
  u16* Qc  = (u16*)(ws + 10485760);           //  8 MB [8192][512] (pre-scaled)
  u16* Kc  = (u16*)(ws + 18874368);           //  8 MB [4*2048][512] compact K
  u16* vtc = (u16*)(ws + 27262976);           //  8 MB [32*64][2048] compact V^T
  int* idx = (int*)(ws + 35651584);           // 32 KB
  int* nbv = (int*)(ws + 35684352);           // 16 B
  u16* aout = xbf;                            // reuse (xbf dead after gemms)

  prep<<<5124, 256, 0, stream>>>(x, Wc, Wo, mask, xbf, wct, wot, idx, nbv);
  gemm64<1><<<dim3(8, 64), 256, 0, stream>>>(
      xbf, wct, bc, Qc, 512, 512, KSCALE_Q);
  gemm_kv<<<dim3(16, 16, 4), 256, 0, stream>>>(
      xbf, wct + (size_t)512 * 512, bc + 512, Kc, vtc, idx, nbv);
  attn_kernel<<<dim3(16, 8, 4), 256, 0, stream>>>(Qc, Kc, vtc, nbv, aout);
  gemm64<0><<<dim3(8, 64), 256, 0, stream>>>(
      aout, wot, bo, out, 512, 512, 1.0f);
}

// Round 5
// 159.029 us; speedup vs baseline: 1.4126x; 1.0588x over previous
//
#include <hip/hip_runtime.h>
#include <hip/hip_bf16.h>
#include <stdint.h>

typedef unsigned short u16;
typedef unsigned int u32;
typedef __attribute__((ext_vector_type(8))) __bf16 bf16x8;
typedef __attribute__((ext_vector_type(8))) unsigned short us8;
typedef __attribute__((ext_vector_type(4))) unsigned short us4;
typedef __attribute__((ext_vector_type(4))) float f32x4;
typedef __attribute__((ext_vector_type(16))) float f32x16;
typedef __attribute__((ext_vector_type(4))) unsigned int u32x4;
typedef __attribute__((ext_vector_type(2))) unsigned int u32x2;

#define KSCALE_Q 0.18033688011112042f  /* (1/8) * log2(e) */

__device__ inline u16 f2bf(float f) {
  union { __bf16 b; u16 s; } x; x.b = (__bf16)f; return x.s;
}
__device__ inline u32 packbf(float a, float b) {
  return (u32)f2bf(a) | ((u32)f2bf(b) << 16);
}
__device__ inline f32x16 zero16() {
  f32x16 z; for (int i = 0; i < 16; ++i) z[i] = 0.f; return z;
}
__device__ __forceinline__ void gl_lds16(const u16* g, u16* l) {
  __builtin_amdgcn_global_load_lds(
      (const __attribute__((address_space(1))) void*)g,
      (__attribute__((address_space(3))) void*)l, 16, 0, 0);
}
// Exchange: new a = [a.lo32 | b.lo32], new b = [a.hi32 | b.hi32]
__device__ __forceinline__ void pl32swap(u32& a, u32& b) {
#if __has_builtin(__builtin_amdgcn_permlane32_swap)
  u32x2 r = __builtin_amdgcn_permlane32_swap(a, b, false, false);
  a = r[0]; b = r[1];
#else
  u32 ta = (u32)__shfl_xor((int)a, 32);
  u32 tb = (u32)__shfl_xor((int)b, 32);
  int hi = (threadIdx.x & 63) >> 5;
  u32 na = hi ? tb : a;
  u32 nb = hi ? b : ta;
  a = na; b = nb;
#endif
}

// ---------------------------------------------------------------- prep (fused)
__global__ __launch_bounds__(256) void prep(
    const float* __restrict__ x, const float* __restrict__ Wc,
    const float* __restrict__ Wo, const int* __restrict__ mask,
    u16* __restrict__ xbf, u16* __restrict__ wct, u16* __restrict__ wot,
    int* __restrict__ idx, int* __restrict__ nbv) {
  int r = blockIdx.x, tid = threadIdx.x;
  if (r < 4096) {
    int i = r * 256 + tid;
    float4 v = ((const float4*)x)[i];
    us4 o;
    o[0] = f2bf(v.x); o[1] = f2bf(v.y); o[2] = f2bf(v.z); o[3] = f2bf(v.w);
    ((us4*)xbf)[i] = o;
    return;
  }
  __shared__ float tile[32][33];
  __shared__ int ps[256];
  if (r < 5120) {
    const float* in; u16* outT; int R, C, bi;
    if (r < 4864) { in = Wc; outT = wct; R = 512; C = 1536; bi = r - 4096; }
    else          { in = Wo; outT = wot; R = 512; C = 512;  bi = r - 4864; }
    int nbx = C >> 5;
    int bx = bi % nbx, by = bi / nbx;
    int xq = tid & 31, yq = tid >> 5;
    int c0 = bx * 32, r0 = by * 32;
    for (int j = 0; j < 32; j += 8)
      tile[yq + j][xq] = in[(size_t)(r0 + yq + j) * C + c0 + xq];
    __syncthreads();
    for (int j = 0; j < 32; j += 8)
      outT[(size_t)(c0 + yq + j) * R + r0 + xq] = f2bf(tile[xq][yq + j]);
    return;
  }
  int b = r - 5120;
  const int* mrow = mask + b * 2048;
  int4 a = ((const int4*)mrow)[tid * 2];
  int4 c = ((const int4*)mrow)[tid * 2 + 1];
  int v[8] = {a.x, a.y, a.z, a.w, c.x, c.y, c.z, c.w};
  int cnt = 0;
  for (int i = 0; i < 8; ++i) cnt += (v[i] > 0);
  ps[tid] = cnt;
  __syncthreads();
  for (int off = 1; off < 256; off <<= 1) {
    int xv = ps[tid];
    int yv = (tid >= off) ? ps[tid - off] : 0;
    __syncthreads();
    ps[tid] = xv + yv;
    __syncthreads();
  }
  int total = ps[255];
  int pos = ps[tid] - cnt;
  int* ip = idx + b * 2048;
  for (int i = 0; i < 8; ++i)
    if (v[i] > 0) ip[pos++] = tid * 8 + i;
  for (int i = 0; i < 8; ++i) {
    int j = tid * 8 + i;
    if (j >= total) ip[j] = 0;
  }
  if (tid == 0) nbv[b] = total;
}

// ---------------------------------------------------------------- GEMM 128x64
// BK=64: 8 k-iters for K=512. XOR-swizzled global_load_lds staging.
template <int OB>
__global__ __launch_bounds__(256) void gemm64(
    const u16* __restrict__ A, const u16* __restrict__ Bt,
    const float* __restrict__ bias, void* __restrict__ Cout,
    int N, int K, float oscale) {
  int m0 = blockIdx.y * 128, n0 = blockIdx.x * 64;
  __shared__ __align__(16) u16 As[128 * 64];  // 16 KB
  __shared__ __align__(16) u16 Bs[64 * 64];   //  8 KB
  int tid = threadIdx.x, wave = tid >> 6, lane = tid & 63;
  int quad = lane >> 4, l16 = lane & 15;
  int wm = (wave >> 1) * 64, wn = (wave & 1) * 32;

  int r8 = lane >> 3;            // row within 8-group
  int cb = (lane & 7) ^ r8;      // 16B content block (XOR row&7)
  const u16* ag = A + (size_t)(m0 + wave * 32 + r8) * K + cb * 8;
  const u16* bg = Bt + (size_t)(n0 + wave * 16 + r8) * K + cb * 8;
  u16* al = As + (wave * 32) * 64 + lane * 8;
  u16* bl = Bs + (wave * 16) * 64 + lane * 8;

  f32x4 acc[4][2];
  for (int i = 0; i < 4; ++i)
    for (int j = 0; j < 2; ++j) acc[i][j] = (f32x4){0.f, 0.f, 0.f, 0.f};

  int rx = l16 & 7;
  for (int kk = 0; kk < K; kk += 64) {
    __syncthreads();
    for (int i = 0; i < 4; ++i)
      gl_lds16(ag + kk + (size_t)(i * 8) * K, al + i * 8 * 64);
    for (int i = 0; i < 2; ++i)
      gl_lds16(bg + kk + (size_t)(i * 8) * K, bl + i * 8 * 64);
    __syncthreads();
    for (int ks = 0; ks < 2; ++ks) {
      int pos = ((ks * 4 + quad) ^ rx) * 8;
      bf16x8 af[4], bfr[2];
      for (int i = 0; i < 4; ++i)
        af[i] = *(const bf16x8*)(As + (wm + i * 16 + l16) * 64 + pos);
      for (int j = 0; j < 2; ++j)
        bfr[j] = *(const bf16x8*)(Bs + (wn + j * 16 + l16) * 64 + pos);
      for (int i = 0; i < 4; ++i)
        for (int j = 0; j < 2; ++j)
          acc[i][j] = __builtin_amdgcn_mfma_f32_16x16x32_bf16(
              af[i], bfr[j], acc[i][j], 0, 0, 0);
    }
  }
  for (int j = 0; j < 2; ++j) {
    int col = n0 + wn + j * 16 + l16;
    float bv = bias[col];
    for (int i = 0; i < 4; ++i) {
      int rowb = m0 + wm + i * 16 + quad * 4;
      for (int rr = 0; rr < 4; ++rr) {
        float v = (acc[i][j][rr] + bv) * oscale;
        if (OB)
          ((u16*)Cout)[(size_t)(rowb + rr) * N + col] = f2bf(v);
        else
          ((float*)Cout)[(size_t)(rowb + rr) * N + col] = v;
      }
    }
  }
}

// ---------------------------------------------------------------- KV GEMM
// Gathered rows. cols<512 -> Kc[b*2048+key][512]; cols>=512 -> V transposed
// into VTc[(b*8+h)*64+d][2048] at [key].
__global__ __launch_bounds__(256) void gemm_kv(
    const u16* __restrict__ A, const u16* __restrict__ Bt,
    const float* __restrict__ bias, u16* __restrict__ Kc,
    u16* __restrict__ VTc, const int* __restrict__ idx,
    const int* __restrict__ nbv) {
  const int K = 512, N = 1024;
  int b = blockIdx.z;
  int m0 = blockIdx.y * 128, n0 = blockIdx.x * 64;
  int npad = (nbv[b] + 127) & ~127;
  if (m0 >= npad) return;
  __shared__ __align__(16) u16 As[128 * 64];
  __shared__ __align__(16) u16 Bs[64 * 64];
  int tid = threadIdx.x, wave = tid >> 6, lane = tid & 63;
  int quad = lane >> 4, l16 = lane & 15;
  int wm = (wave >> 1) * 64, wn = (wave & 1) * 32;

  int r8 = lane >> 3;
  int cb = (lane & 7) ^ r8;
  const u16* agp[4];
  for (int i = 0; i < 4; ++i) {
    int gi = idx[b * 2048 + m0 + wave * 32 + i * 8 + r8];
    agp[i] = A + (size_t)(b * 2048 + gi) * K + cb * 8;
  }
  const u16* bg = Bt + (size_t)(n0 + wave * 16 + r8) * K + cb * 8;
  u16* al = As + (wave * 32) * 64 + lane * 8;
  u16* bl = Bs + (wave * 16) * 64 + lane * 8;

  f32x4 acc[4][2];
  for (int i = 0; i < 4; ++i)
    for (int j = 0; j < 2; ++j) acc[i][j] = (f32x4){0.f, 0.f, 0.f, 0.f};

  int rx = l16 & 7;
  for (int kk = 0; kk < K; kk += 64) {
    __syncthreads();
    for (int i = 0; i < 4; ++i)
      gl_lds16(agp[i] + kk, al + i * 8 * 64);
    for (int i = 0; i < 2; ++i)
      gl_lds16(bg + kk + (size_t)(i * 8) * K, bl + i * 8 * 64);
    __syncthreads();
    for (int ks = 0; ks < 2; ++ks) {
      int pos = ((ks * 4 + quad) ^ rx) * 8;
      bf16x8 af[4], bfr[2];
      for (int i = 0; i < 4; ++i)
        af[i] = *(const bf16x8*)(As + (wm + i * 16 + l16) * 64 + pos);
      for (int j = 0; j < 2; ++j)
        bfr[j] = *(const bf16x8*)(Bs + (wn + j * 16 + l16) * 64 + pos);
      for (int i = 0; i < 4; ++i)
        for (int j = 0; j < 2; ++j)
          acc[i][j] = __builtin_amdgcn_mfma_f32_16x16x32_bf16(
              af[i], bfr[j], acc[i][j], 0, 0, 0);
    }
  }
  for (int j = 0; j < 2; ++j) {
    int col = n0 + wn + j * 16 + l16;
    float bv = bias[col];
    if (col < 512) {
      for (int i = 0; i < 4; ++i) {
        int key0 = m0 + wm + i * 16 + quad * 4;
        for (int rr = 0; rr < 4; ++rr)
          Kc[((size_t)b * 2048 + key0 + rr) * 512 + col] =
              f2bf(acc[i][j][rr] + bv);
      }
    } else {
      int hd = col - 512;
      int h = hd >> 6, d = hd & 63;
      u16* vrow = VTc + ((size_t)(b * 8 + h) * 64 + d) * 2048;
      for (int i = 0; i < 4; ++i) {
        int key0 = m0 + wm + i * 16 + quad * 4;
        us4 pk;
        for (int rr = 0; rr < 4; ++rr) pk[rr] = f2bf(acc[i][j][rr] + bv);
        *(us4*)(vrow + key0) = pk;
      }
    }
  }
}

// ---------------------------------------------------------------- attention
// 32x32x16 MFMA flash, 128-key tiles, wave = 32 q. P transform C->B operand
// via permlane32_swap (no LDS round-trip). No-max exp2 softmax.
__global__ __launch_bounds__(256) void attn_kernel(
    const u16* __restrict__ Qc, const u16* __restrict__ Kc,
    const u16* __restrict__ VTc, const int* __restrict__ nbv,
    u16* __restrict__ aout) {
  int b = blockIdx.z, h = blockIdx.y, q0 = blockIdx.x * 128;
  int bh = b * 8 + h;
  int tid = threadIdx.x, wave = tid >> 6, lane = tid & 63;
  int l5 = lane & 31, hi = lane >> 5;
  int nb = nbv[b];
  int npad = (nb + 127) & ~127;

  __shared__ __align__(16) u16 Kt[128 * 64];  // [key][d], XOR8 16B blocks
  __shared__ __align__(16) u16 Vt[64 * 128];  // [d][key], XOR16 16B blocks

  int qrow = b * 2048 + q0 + wave * 32 + l5;
  bf16x8 qf[4];  // B-op: k = s*16 + hi*8 + j
  for (int s = 0; s < 4; ++s)
    qf[s] = *(const bf16x8*)(Qc + (size_t)qrow * 512 + h * 64 + s * 16 + hi * 8);

  f32x16 o[2];
  o[0] = zero16(); o[1] = zero16();
  float lsum = 0.f;

  // K staging: 8 rows/instr (128B rows), 4 instrs; V: 4 rows/instr (256B rows)
  int krr = lane >> 3;
  int kcb = (lane & 7) ^ krr;
  const u16* kg = Kc + ((size_t)(b * 2048) + wave * 32 + krr) * 512 + h * 64 +
                  kcb * 8;
  u16* kl = Kt + (wave * 32) * 64 + lane * 8;
  int vrr = lane >> 4;
  u16* vl = Vt + (wave * 16) * 128 + lane * 8;

  for (int kt0 = 0; kt0 < npad; kt0 += 128) {
    __syncthreads();
    for (int i = 0; i < 4; ++i)
      gl_lds16(kg + (size_t)(kt0 + i * 8) * 512, kl + i * 8 * 64);
    for (int i = 0; i < 4; ++i) {
      int vr = wave * 16 + i * 4 + vrr;
      int vcb = (lane & 15) ^ (vr & 15);
      gl_lds16(VTc + ((size_t)(bh * 64) + vr) * 2048 + kt0 + vcb * 8,
               vl + i * 4 * 128);
    }
    __syncthreads();

    for (int kg4 = 0; kg4 < 4; ++kg4) {
      int krow = kg4 * 32 + l5;
      const u16* kro = Kt + krow * 64;
      int rx = krow & 7;
      f32x16 sa = zero16();
      for (int s = 0; s < 4; ++s) {
        bf16x8 ka = *(const bf16x8*)(kro + ((s * 2 + hi) ^ rx) * 8);
        sa = __builtin_amdgcn_mfma_f32_32x32x16_bf16(ka, qf[s], sa, 0, 0, 0);
      }
      if (kt0 + 128 > nb) {  // uniform: only final tile masks
        for (int r = 0; r < 16; ++r) {
          int jg = kt0 + kg4 * 32 + (r & 3) + 8 * (r >> 2) + 4 * hi;
          if (jg >= nb) sa[r] = -1e30f;
        }
      }
      u32 pk[8];
      for (int j = 0; j < 8; ++j) {
        float e0 = __builtin_amdgcn_exp2f(sa[2 * j]);
        float e1 = __builtin_amdgcn_exp2f(sa[2 * j + 1]);
        lsum += e0 + e1;
        pk[j] = packbf(e0, e1);
      }
      for (int t = 0; t < 2; ++t) {
        u32 a0 = pk[t * 4 + 0], a2 = pk[t * 4 + 2];
        u32 a1 = pk[t * 4 + 1], a3 = pk[t * 4 + 3];
        pl32swap(a0, a2);
        pl32swap(a1, a3);
        u32x4 qv; qv[0] = a0; qv[1] = a1; qv[2] = a2; qv[3] = a3;
        bf16x8 pb = __builtin_bit_cast(bf16x8, qv);
        int cblk = kg4 * 4 + t * 2 + hi;
        for (int dc = 0; dc < 2; ++dc) {
          int vrow = dc * 32 + l5;
          bf16x8 va = *(const bf16x8*)(Vt + vrow * 128 +
                                       ((cblk ^ (vrow & 15)) * 8));
          o[dc] = __builtin_amdgcn_mfma_f32_32x32x16_bf16(va, pb, o[dc],
                                                          0, 0, 0);
        }
      }
    }
  }

  lsum += __shfl_xor(lsum, 32);
  float inv = 1.f / lsum;
  for (int dc = 0; dc < 2; ++dc)
    for (int mI = 0; mI < 4; ++mI) {
      us4 pk;
      for (int r = 0; r < 4; ++r) pk[r] = f2bf(o[dc][mI * 4 + r] * inv);
      *(us4*)(aout + (size_t)qrow * 512 + h * 64 + dc * 32 + mI * 8 + hi * 4) =
          pk;
    }
}

// ---------------------------------------------------------------- launch
extern "C" void kernel_launch(void* const* d_in, const int* in_sizes, int n_in,
                              void* d_out, int out_size, void* d_ws,
                              size_t ws_size, hipStream_t stream) {
  const float* x = (const float*)d_in[0];     // [4,2048,512]
  const int* mask = (const int*)d_in[1];      // [4,2048]
  const float* Wc = (const float*)d_in[2];    // [512,1536]
  const float* bc = (const float*)d_in[3];    // [1536]
  const float* Wo = (const float*)d_in[4];    // [512,512]
  const float* bo = (const float*)d_in[5];    // [512]
  float* out = (float*)d_out;                 // [4,2048,512] fp32

  char* ws = (char*)d_ws;
  u16* xbf = (u16*)(ws);                      //  8 MB [8192][512]
  u16* wct = (u16*)(ws + 8388608);            //  1.5 MB [1536][512]
  u16* wot = (u16*)(ws + 9961472);            //  0.5 MB [512][512]
  u16* Qc  = (u16*)(ws + 10485760);           //  8 MB (pre-scaled by log2e/8)
  u16* Kc  = (u16*)(ws + 18874368);           //  8 MB compact K
  u16* vtc = (u16*)(ws + 27262976);           //  8 MB compact V^T
  int* idx = (int*)(ws + 35651584);           // 32 KB
  int* nbv = (int*)(ws + 35684352);           // 16 B
  u16* aout = xbf;                            // reuse (xbf dead after gemms)

  prep<<<5124, 256, 0, stream>>>(x, Wc, Wo, mask, xbf, wct, wot, idx, nbv);
  gemm64<1><<<dim3(8, 64), 256, 0, stream>>>(
      xbf, wct, bc, Qc, 512, 512, KSCALE_Q);
  gemm_kv<<<dim3(16, 16, 4), 256, 0, stream>>>(
      xbf, wct + (size_t)512 * 512, bc + 512, Kc, vtc, idx, nbv);
  attn_kernel<<<dim3(16, 8, 4), 256, 0, stream>>>(Qc, Kc, vtc, nbv, aout);
  gemm64<0><<<dim3(8, 64), 256, 0, stream>>>(
      aout, wot, bo, out, 512, 512, 1.0f);
}